// Round 5
// baseline (1743.199 us; speedup 1.0000x reference)
//
#include <hip/hip_runtime.h>
#include <stdint.h>

#define NROWS 4096   // S*B
#define HDIM  512
#define GDIM  2048   // 4*H
#define WWIN  32

typedef __attribute__((ext_vector_type(8))) short short8;
typedef __attribute__((ext_vector_type(4))) float f32x4;

__device__ __forceinline__ unsigned short f2bf(float x){
  union { float f; unsigned int u; } v; v.f = x;
  unsigned int u = v.u + 0x7fffu + ((v.u >> 16) & 1u);
  return (unsigned short)(u >> 16);
}
__device__ __forceinline__ float bf2f(unsigned short u){
  union { unsigned int u; float f; } v; v.u = ((unsigned int)u) << 16; return v.f;
}

__device__ __forceinline__ void gld16(const void* g, void* l){
  __builtin_amdgcn_global_load_lds(
      (const __attribute__((address_space(1))) unsigned int*)g,
      (__attribute__((address_space(3))) unsigned int*)l, 16, 0, 0);
}

__device__ __forceinline__ float sigm(float x){ return 1.f/(1.f + __expf(-x)); }
__device__ __forceinline__ float tanh_f(float x){ return 1.f - 2.f/(1.f + __expf(2.f*x)); }

// ---- per-band sync: 4 blocks (L0/L1 x 2 halves) share one monotonic counter --
// h moves via agent-relaxed atomics (coherent, bypasses L2) -> no cache fences
// needed; __syncthreads drains each wave's stores before arrival. Bands are
// fully independent (LSTM recurrence is row-local) -> no global convoy.
__device__ __forceinline__ void band_sync(unsigned* ctr, unsigned target){
  __syncthreads();
  if (threadIdx.x == 0){
    __hip_atomic_fetch_add(ctr, 1u, __ATOMIC_RELAXED, __HIP_MEMORY_SCOPE_AGENT);
    while (__hip_atomic_load(ctr, __ATOMIC_RELAXED, __HIP_MEMORY_SCOPE_AGENT) < target)
      __builtin_amdgcn_s_sleep(2);
  }
  asm volatile("" ::: "memory");
  __syncthreads();
}

// ------------- double-buffered 128x128 GEMM core (bf16, BT weight layout) -----
// (p0_gemm only)
__device__ __forceinline__ void gemm_tile_db(
    const char* A0, const char* A1, const char* Bsrc,
    int ldbB, int nk, int r0, int c0,
    char* smem, int wr, int wc, int lane, f32x4 acc[4][4])
{
  const int tid = threadIdx.x;
  const int oo0 = tid * 16;
  const int srow = oo0 >> 7;
  const int scb  = oo0 & 127;
  const size_t aOff = (size_t)(r0 + srow) * 1024 + scb;
  const size_t bOff = (size_t)(c0 + srow) * (size_t)ldbB + scb;

  auto STAGE = [&](int kk, int buf){
    const char* Ap = (kk < 8) ? A0 : A1;
    const size_t kbA = (size_t)(kk & 7) * 128;
    const size_t kbB = (size_t)kk * 128;
    char* AsB = smem + buf * 16384;
    char* BsB = smem + 32768 + buf * 16384;
    #pragma unroll
    for (int i = 0; i < 4; ++i){
      const size_t rstep = (size_t)i * 32;
      gld16(Ap   + aOff + rstep * 1024          + kbA, AsB + i*4096 + oo0);
      gld16(Bsrc + bOff + rstep * (size_t)ldbB  + kbB, BsB + i*4096 + oo0);
    }
  };

  STAGE(0, 0);
  __syncthreads();

  const int lr = lane & 15;
  const int lk = (lane >> 4) * 8;

  for (int kk = 0; kk < nk; ++kk){
    const int cur = kk & 1;
    if (kk + 1 < nk) STAGE(kk + 1, cur ^ 1);

    const unsigned short* As = (const unsigned short*)(smem + cur*16384);
    const unsigned short* Bs = (const unsigned short*)(smem + 32768 + cur*16384);
    short8 a[2][4], b[2][4];
    #pragma unroll
    for (int h = 0; h < 2; ++h){
      const int k32 = h * 32;
      #pragma unroll
      for (int m = 0; m < 4; ++m)
        a[h][m] = *(const short8*)(As + (64*wr + 16*m + lr)*64 + k32 + lk);
      #pragma unroll
      for (int n = 0; n < 4; ++n)
        b[h][n] = *(const short8*)(Bs + (64*wc + 16*n + lr)*64 + k32 + lk);
    }
    __builtin_amdgcn_s_setprio(1);
    #pragma unroll
    for (int h = 0; h < 2; ++h)
      #pragma unroll
      for (int m = 0; m < 4; ++m)
        #pragma unroll
        for (int n = 0; n < 4; ++n)
          acc[m][n] = __builtin_amdgcn_mfma_f32_16x16x32_bf16(a[h][m], b[h][n], acc[m][n], 0, 0, 0);
    __builtin_amdgcn_s_setprio(0);

    __syncthreads();
  }
}

// ---------------- prep: reorder weights gate-interleaved, cast bf16 -----------
__global__ void __launch_bounds__(256) prep_weights(
    const float* wih0, const float* whh0, const float* bih0, const float* bhh0,
    const float* wih1, const float* whh1, const float* bih1, const float* bhh1,
    unsigned short* BrIh0, unsigned short* Br0, unsigned short* Br1,
    float* bias0r, float* br1)
{
  const int j = blockIdx.x;
  const int g = j & 3, hd = j >> 2;
  const int r = g*512 + hd;
  for (int k = threadIdx.x; k < 512; k += 256){
    BrIh0[(size_t)j*512 + k]      = f2bf(wih0[(size_t)r*512 + k]);
    Br0  [(size_t)j*512 + k]      = f2bf(whh0[(size_t)r*512 + k]);
    Br1  [(size_t)j*1024 + k]     = f2bf(wih1[(size_t)r*512 + k]);
    Br1  [(size_t)j*1024 + 512+k] = f2bf(whh1[(size_t)r*512 + k]);
  }
  if (threadIdx.x == 0){
    bias0r[j] = bih0[r] + bhh0[r];
    br1[j]    = bih1[r] + bhh1[r];
  }
}

// ---------------- embedding gather (fp32 -> bf16) -----------------------------
__global__ void __launch_bounds__(256) gather_embed(const int* enc, const float* tbl,
                                                    unsigned short* E)
{
  const int n = blockIdx.x;
  const int idx = enc[n];
  const float* src = tbl + (size_t)idx * 512;
  unsigned short* dst = E + (size_t)n * 512;
  for (int e = threadIdx.x; e < 512; e += 256) dst[e] = f2bf(src[e]);
}

// ---------------- P0 = E @ BrIh0^T + bias0r (bf16 out, interleaved cols) ------
__global__ void __launch_bounds__(256) p0_gemm(const unsigned short* E,
                                               const unsigned short* BrIh0,
                                               const float* bias0r,
                                               unsigned short* P0)
{
  __shared__ __align__(16) char smem[65536];
  const int tid  = threadIdx.x;
  const int lane = tid & 63, wid = tid >> 6;
  const int wr = wid >> 1, wc = wid & 1;
  const int bid = blockIdx.x;
  const int r0 = (bid >> 4) * 128, c0 = (bid & 15) * 128;
  f32x4 acc[4][4] = {};
  gemm_tile_db((const char*)E, nullptr, (const char*)BrIh0, 1024, 8,
               r0, c0, smem, wr, wc, lane, acc);
  #pragma unroll
  for (int m = 0; m < 4; ++m){
    const int rowb = r0 + 64*wr + 16*m + ((lane >> 4) << 2);
    #pragma unroll
    for (int n = 0; n < 4; ++n){
      const int colb = c0 + 64*wc + 16*n + (lane & 15);
      const float bs = bias0r[colb];
      #pragma unroll
      for (int r = 0; r < 4; ++r)
        P0[(size_t)(rowb + r)*GDIM + colb] = f2bf(acc[m][n][r] + bs);
    }
  }
}

// ============== persistent fused kernel v3: 64x1024 tiles =====================
// 256 blocks x 512 thr, 1/CU, 8 waves (1x8 over gates), wave tile 64x128,
// acc[4][8]. h-band read redundancy = 2 (two gate-halves) vs 8 before:
// h traffic 96 -> 24 MB/step. Weights: per XCD exactly one (layer,half) combo
// (bid%8 mapping) = 1-2MB, L2-resident; streamed per kt as 64KB gld16 ring-2.
// A (h) = 4KB/kt, reg-staged 2 kts ahead via agent atomics + swizzled
// ds_write_b64. K-step 32. LDS: A 2x4KB @0, B 2x64KB @16K = 144KB.
// Swizzle: 128B lines pack 2 rows (4 slot8 each); phys slot8 = logical ^
// (line&7) on BOTH write/source and read (rule #21).
__global__ void __launch_bounds__(512, 1) persist_kernel(
    unsigned short* h0, unsigned short* h1,
    const unsigned short* Br0, const unsigned short* Br1,
    const unsigned short* P0, const float* br1, float* out, unsigned* bar)
{
  extern __shared__ __align__(16) char smem[];

  const int bid  = blockIdx.x;
  const int x    = bid & 7;            // XCD (bid%8 round-robin heuristic)
  const int s    = bid >> 3;           // 0..31
  const bool L1  = (x & 1);
  const int half = (x >> 1) & 1;
  const int band = ((x >> 2) << 5) + s;   // 0..63 (64 rows each)
  const int r0   = band * 64;
  const int gbase  = half * 1024;      // gate-col base
  const int hdbase = half * 256;       // hd base (contiguous 256 hd per block)

  const int tid  = threadIdx.x;
  const int lane = tid & 63, wn = tid >> 6;    // 8 waves, 1x8 over gates
  const int lr = lane & 15, sl = lane >> 4;

  // B staging constants (linear gld16 dest; inverse-swizzled global source)
  const int sb8   = (tid & 7) ^ ((tid >> 3) & 7);
  const int kslB  = sb8 & 3;
  const int rhiB  = sb8 >> 2;
  const int trlB  = (tid >> 3) << 1;
  // A staging constants (reg->ds_write_b64, swizzled dest)
  const int ar  = tid >> 3;            // row 0..63
  const int ac  = tid & 7;             // 8B chunk 0..7
  const int alin  = ar >> 1;
  const int asl8  = (((ar & 1) << 2) + (ac >> 1)) ^ (alin & 7);
  const int awoff = alin*128 + asl8*16 + (ac & 1)*8;

  const char* Bp  = (const char*)(L1 ? Br1 : Br0);
  const int  ldb  = L1 ? 2048 : 1024;  // BT row bytes
  const int  nkt  = L1 ? 32 : 16;      // K-steps of 32

  unsigned* ctr = bar + band * 32;     // 128B-padded per-band counter

  float creg[4][4][2];
  #pragma unroll
  for (int p = 0; p < 4; ++p)
    #pragma unroll
    for (int q = 0; q < 4; ++q){ creg[p][q][0] = 0.f; creg[p][q][1] = 0.f; }

  for (int tau = 0; tau <= 33; ++tau){
    const bool active = L1 ? (tau >= 1) : (tau <= 32);
    if (active){
      const int t  = L1 ? (tau - 1) : tau;
      const int pr = (tau + 1) & 1, pw = tau & 1;
      const unsigned short* hA0 = h0 + (size_t)pr * (NROWS*HDIM);
      const unsigned short* hA1 = h1 + (size_t)pr * (NROWS*HDIM);

      auto issueB = [&](int kt2){
        char* d = smem + 16384 + (size_t)(kt2 & 1) * 65536 + tid * 16;
        const int kb = kt2 * 64 + kslB * 16;
        #pragma unroll
        for (int i = 0; i < 8; ++i){
          const int row = i*128 + trlB + rhiB;
          gld16(Bp + (size_t)(gbase + row) * (size_t)ldb + kb, d + i*8192);
        }
      };
      auto issueA = [&](int kt2, unsigned long long& a){
        const unsigned short* hs; int kE;
        if (!L1 || kt2 < 16){ hs = hA0; kE = kt2 * 32; }
        else                { hs = hA1; kE = (kt2 - 16) * 32; }
        const unsigned long long* p =
            (const unsigned long long*)(hs + (size_t)(r0 + ar) * 512 + kE + ac * 4);
        a = __hip_atomic_load(p, __ATOMIC_RELAXED, __HIP_MEMORY_SCOPE_AGENT);
      };
      auto writeA = [&](int kt2, unsigned long long a){
        *(unsigned long long*)(smem + (size_t)(kt2 & 1) * 4096 + awoff) = a;
      };

      f32x4 acc[4][8] = {};
      unsigned long long areg;

      // prologue: A(0)->LDS, B(0) + A(1) in flight
      issueA(0, areg);
      writeA(0, areg);
      issueB(0);
      issueA(1, areg);
      asm volatile("s_waitcnt vmcnt(1)" ::: "memory");   // B(0) landed
      asm volatile("s_waitcnt lgkmcnt(0)" ::: "memory");
      __builtin_amdgcn_s_barrier();

      for (int kt = 0; kt < nkt; ++kt){
        if (kt + 1 < nkt){
          writeA(kt + 1, areg);         // areg done long ago -> free wait
          issueB(kt + 1);
          if (kt + 2 < nkt) issueA(kt + 2, areg);
        }

        const char* Ab = smem + (size_t)(kt & 1) * 4096;
        const char* Bb = smem + 16384 + (size_t)(kt & 1) * 65536;
        short8 a[4], b[8];
        #pragma unroll
        for (int m = 0; m < 4; ++m){
          const int row = m*16 + lr;
          const int ln  = row >> 1;
          const int p8  = (((row & 1) << 2) + sl) ^ (ln & 7);
          a[m] = *(const short8*)(Ab + ln*128 + p8*16);
        }
        #pragma unroll
        for (int n = 0; n < 8; ++n){
          const int row = wn*128 + n*16 + lr;
          const int ln  = row >> 1;
          const int p8  = (((row & 1) << 2) + sl) ^ (ln & 7);
          b[n] = *(const short8*)(Bb + ln*128 + p8*16);
        }

        __builtin_amdgcn_s_setprio(1);
        #pragma unroll
        for (int m = 0; m < 4; ++m)
          #pragma unroll
          for (int n = 0; n < 8; ++n)
            acc[m][n] = __builtin_amdgcn_mfma_f32_16x16x32_bf16(a[m], b[n], acc[m][n], 0, 0, 0);
        __builtin_amdgcn_s_setprio(0);

        if (kt + 1 < nkt){
          if (kt + 2 < nkt) asm volatile("s_waitcnt vmcnt(1)" ::: "memory");
          else              asm volatile("s_waitcnt vmcnt(0)" ::: "memory");
          asm volatile("s_waitcnt lgkmcnt(0)" ::: "memory");
          __builtin_amdgcn_s_barrier();
        }
      }

      // ---- epilogue: LSTM pointwise, c in regs, h via agent-atomic u32 ----
      float* GLDS = (float*)smem;
      const int GST = 260;             // 64 x 260 x 4B = 66.6KB
      unsigned short* hw = (L1 ? h1 : h0) + (size_t)pw * (NROWS*HDIM);
      const bool finalStep = (L1 && t == 32);

      #pragma unroll
      for (int pass = 0; pass < 4; ++pass){
        __syncthreads();               // drains vmcnt too (epilogue reuses smem)
        if ((wn >> 1) == pass){        // waves 2p, 2p+1 own gates [p*256,p*256+256)
          #pragma unroll
          for (int m = 0; m < 4; ++m){
            const int rowb = m*16 + (sl << 2);
            #pragma unroll
            for (int n = 0; n < 8; ++n){
              const int colb = ((wn & 1) << 7) + n*16 + lr;
              const f32x4 v = acc[m][n];
              #pragma unroll
              for (int r = 0; r < 4; ++r)
                GLDS[(rowb + r)*GST + colb] = v[r];
            }
          }
        }
        __syncthreads();
        #pragma unroll
        for (int it = 0; it < 4; ++it){
          const int pid = it*512 + tid;        // 2048 = 64 rows x 32 hd-pairs
          const int row = pid >> 5;
          const int pl  = (pid & 31) * 2;      // hd-within-pass (pairs)
          const int rowg = r0 + row;
          const int hd0  = hdbase + pass*64 + pl;
          const float* gp = &GLDS[row*GST + 4*pl];
          const float4 g0 = *(const float4*)gp;
          const float4 g1 = *(const float4*)(gp + 4);
          float gi0 = g0.x, gf0 = g0.y, gg0 = g0.z, go0 = g0.w;
          float gi1 = g1.x, gf1 = g1.y, gg1 = g1.z, go1 = g1.w;
          const int sI = rowg >> 3;
          const int bb = rowg & 7;
          const int pos = sI - WWIN + t;
          if (!L1){
            const int p0r = (pos < 0 ? 0 : pos)*8 + bb;
            const uint4 pv = *(const uint4*)&P0[(size_t)p0r*GDIM + 4*hd0];
            gi0 += bf2f((unsigned short)(pv.x & 0xffff));
            gf0 += bf2f((unsigned short)(pv.x >> 16));
            gg0 += bf2f((unsigned short)(pv.y & 0xffff));
            go0 += bf2f((unsigned short)(pv.y >> 16));
            gi1 += bf2f((unsigned short)(pv.z & 0xffff));
            gf1 += bf2f((unsigned short)(pv.z >> 16));
            gg1 += bf2f((unsigned short)(pv.w & 0xffff));
            go1 += bf2f((unsigned short)(pv.w >> 16));
          } else {
            const float4 b0 = *(const float4*)&br1[4*hd0];
            const float4 b1 = *(const float4*)&br1[4*hd0 + 4];
            gi0 += b0.x; gf0 += b0.y; gg0 += b0.z; go0 += b0.w;
            gi1 += b1.x; gf1 += b1.y; gg1 += b1.z; go1 += b1.w;
          }
          float cp0 = creg[pass][it][0];
          float cp1 = creg[pass][it][1];
          float i0 = sigm(gi0), f0 = sigm(gf0), gA = tanh_f(gg0), o0 = sigm(go0);
          float i1 = sigm(gi1), f1 = sigm(gf1), gB = tanh_f(gg1), o1 = sigm(go1);
          float cn0 = f0*cp0 + i0*gA;
          float cn1 = f1*cp1 + i1*gB;
          float hn0 = o0*tanh_f(cn0);
          float hn1 = o1*tanh_f(cn1);
          if (pos < 0){ cn0 = 0.f; hn0 = 0.f; cn1 = 0.f; hn1 = 0.f; }
          creg[pass][it][0] = cn0;
          creg[pass][it][1] = cn1;
          const size_t sidx0 = (size_t)rowg*HDIM + hd0;
          if (finalStep){
            *(float2*)&out[sidx0] = make_float2(hn0, hn1);
          } else {
            const unsigned hp = (unsigned)f2bf(hn0) | ((unsigned)f2bf(hn1) << 16);
            __hip_atomic_store((unsigned*)&hw[sidx0], hp, __ATOMIC_RELAXED,
                               __HIP_MEMORY_SCOPE_AGENT);
          }
        }
      }
    }
    if (tau != 33) band_sync(ctr, 4u * (unsigned)(tau + 1));
  }
}

// ---------------- fallback per-step kernel (non-cooperative path) -------------
__global__ void __launch_bounds__(512, 2) step_kernel(
    unsigned short* h0, unsigned short* h1, float* c0b, float* c1b,
    const unsigned short* Br0, const unsigned short* Br1,
    const unsigned short* P0, const float* br1, float* out, int tau, int bidOff)
{
  extern __shared__ __align__(16) char smem[];

  const int x = blockIdx.x & 7, kq = blockIdx.x >> 3;
  int wk;
  if (gridDim.x == 256) wk = ((kq & 1) << 7) + x * 16 + (kq >> 1);
  else                  wk = x * 16 + kq;
  wk += bidOff;

  const bool L1 = (wk >= 128);
  const int t  = L1 ? (tau - 1) : tau;
  const int pr = (tau + 1) & 1, pw = tau & 1;
  const int lb = L1 ? (wk - 128) : wk;
  const int r0  = (lb >> 3) * 256;
  const int c0v = (lb & 7) * 256;

  const int tid  = threadIdx.x;
  const int lane = tid & 63;
  const int wid  = tid >> 6;
  const int wm = wid >> 2, wn = wid & 3;
  const int lr = lane & 15, sl = lane >> 4;

  const unsigned short* hA0 = h0 + (size_t)pr * (NROWS*HDIM);
  const unsigned short* hA1 = h1 + (size_t)pr * (NROWS*HDIM);
  const char* Bp  = (const char*)(L1 ? Br1 : Br0);
  const int  ldbB = L1 ? 2048 : 1024;
  const int  nkt  = L1 ? 32 : 16;

  const int srow  = tid >> 2;
  const int sbyte = ((tid & 3) ^ ((tid >> 3) & 3)) << 4;
  const int ph    = (sl ^ ((lr >> 1) & 3)) << 4;
  const int laneA = (wm*128 + lr) * 64 + ph;
  const int laneB = (wn*64  + lr) * 64 + ph;

  auto STAGE_A = [&](int kt2, int c){
    const char* Ap; int kB;
    if (!L1 || kt2 < 16){ Ap = (const char*)hA0; kB = kt2 * 64; }
    else                { Ap = (const char*)hA1; kB = (kt2 - 16) * 64; }
    gld16(Ap + (size_t)(r0 + c*128 + srow) * 1024 + kB + sbyte,
          smem + (size_t)(kt2 & 3) * 32768 + c*8192 + tid*16);
  };
  auto STAGE_B = [&](int kt2, int c){
    gld16(Bp + (size_t)(c0v + c*128 + srow) * (size_t)ldbB + kt2*64 + sbyte,
          smem + (size_t)(kt2 & 3) * 32768 + 16384 + c*8192 + tid*16);
  };

  f32x4 acc[8][4] = {};

  STAGE_A(0,0); STAGE_A(0,1); STAGE_B(0,0); STAGE_B(0,1);
  STAGE_A(1,0); STAGE_A(1,1); STAGE_B(1,0); STAGE_B(1,1);
  asm volatile("s_waitcnt vmcnt(4)" ::: "memory");
  __builtin_amdgcn_s_barrier();

  for (int kt = 0; kt < nkt; ++kt){
    const char* bufp = smem + (size_t)(kt & 3) * 32768;
    const bool st = (kt + 2) < nkt;
    short8 a0[4], a1[4], b[4];

    #pragma unroll
    for (int m = 0; m < 4; ++m) a0[m] = *(const short8*)(bufp + laneA + m*1024);
    #pragma unroll
    for (int n = 0; n < 4; ++n) b[n]  = *(const short8*)(bufp + 16384 + laneB + n*1024);
    if (st){ STAGE_A(kt+2, 0); STAGE_A(kt+2, 1); }
    __builtin_amdgcn_s_barrier();
    asm volatile("s_waitcnt lgkmcnt(0)" ::: "memory");
    __builtin_amdgcn_sched_barrier(0);
    __builtin_amdgcn_s_setprio(1);
    #pragma unroll
    for (int m = 0; m < 4; ++m)
      #pragma unroll
      for (int n = 0; n < 4; ++n)
        acc[m][n] = __builtin_amdgcn_mfma_f32_16x16x32_bf16(a0[m], b[n], acc[m][n], 0, 0, 0);
    __builtin_amdgcn_s_setprio(0);
    __builtin_amdgcn_s_barrier();

    #pragma unroll
    for (int m = 0; m < 4; ++m) a1[m] = *(const short8*)(bufp + laneA + (4+m)*1024);
    if (st){
      STAGE_B(kt+2, 0); STAGE_B(kt+2, 1);
      asm volatile("s_waitcnt vmcnt(4)" ::: "memory");
    } else {
      asm volatile("s_waitcnt vmcnt(0)" ::: "memory");
    }
    __builtin_amdgcn_s_barrier();
    asm volatile("s_waitcnt lgkmcnt(0)" ::: "memory");
    __builtin_amdgcn_sched_barrier(0);
    __builtin_amdgcn_s_setprio(1);
    #pragma unroll
    for (int m = 0; m < 4; ++m)
      #pragma unroll
      for (int n = 0; n < 4; ++n)
        acc[4+m][n] = __builtin_amdgcn_mfma_f32_16x16x32_bf16(a1[m], b[n], acc[4+m][n], 0, 0, 0);
    __builtin_amdgcn_s_setprio(0);
    __builtin_amdgcn_s_barrier();
  }

  float* GLDS = (float*)smem;
  const int GST = 68;
  float* cbuf = L1 ? c1b : c0b;
  unsigned short* hw = (L1 ? h1 : h0) + (size_t)pw * (NROWS*HDIM);
  const bool finalStep = (L1 && t == 32);

  for (int pass = 0; pass < 4; ++pass){
    __syncthreads();
    if (wn == pass){
      #pragma unroll
      for (int m = 0; m < 8; ++m){
        const int rowb = wm*128 + m*16 + (sl << 2);
        #pragma unroll
        for (int n = 0; n < 4; ++n){
          const int colb = n*16 + lr;
          const f32x4 v = acc[m][n];
          #pragma unroll
          for (int r = 0; r < 4; ++r)
            GLDS[(rowb + r)*GST + colb] = v[r];
        }
      }
    }
    __syncthreads();
    #pragma unroll
    for (int it = 0; it < 8; ++it){
      const int cid = it*512 + tid;
      const int row = cid >> 4;
      const int l   = cid & 15;
      const int rowg = r0 + row;
      const int hd   = (c0v >> 2) + pass*16 + l;
      float4 gv = *(const float4*)&GLDS[row*GST + 4*l];
      float gi = gv.x, gf = gv.y, gg = gv.z, go = gv.w;
      const int s  = rowg >> 3;
      const int bb = rowg & 7;
      const int pos = s - WWIN + t;
      if (!L1){
        const int p0r = (pos < 0 ? 0 : pos)*8 + bb;
        const ushort4 pv = *(const ushort4*)&P0[(size_t)p0r*GDIM + 4*hd];
        gi += bf2f(pv.x); gf += bf2f(pv.y); gg += bf2f(pv.z); go += bf2f(pv.w);
      } else {
        float4 bv = *(const float4*)&br1[4*hd];
        gi += bv.x; gf += bv.y; gg += bv.z; go += bv.w;
      }
      const size_t sidx = (size_t)rowg*HDIM + hd;
      float cp = cbuf[sidx];
      float i_ = sigm(gi), f_ = sigm(gf), g_ = tanh_f(gg), o_ = sigm(go);
      float cn = f_*cp + i_*g_;
      float hn = o_*tanh_f(cn);
      if (pos < 0){ cn = 0.f; hn = 0.f; }
      cbuf[sidx] = cn;
      if (finalStep) out[sidx] = hn;
      else           hw[sidx]  = f2bf(hn);
    }
  }
}

extern "C" void kernel_launch(void* const* d_in, const int* in_sizes, int n_in,
                              void* d_out, int out_size, void* d_ws, size_t ws_size,
                              hipStream_t stream)
{
  const int*   enc  = (const int*)d_in[0];
  const float* tbl  = (const float*)d_in[1];
  const float* wih0 = (const float*)d_in[2];
  const float* whh0 = (const float*)d_in[3];
  const float* bih0 = (const float*)d_in[4];
  const float* bhh0 = (const float*)d_in[5];
  const float* wih1 = (const float*)d_in[6];
  const float* whh1 = (const float*)d_in[7];
  const float* bih1 = (const float*)d_in[8];
  const float* bhh1 = (const float*)d_in[9];
  float* out = (float*)d_out;

  char* ws = (char*)d_ws;
  size_t off = 0;
  auto alloc = [&](size_t bytes){
    char* p = ws + off; off += (bytes + 255) & ~(size_t)255; return p;
  };
  unsigned short* E     = (unsigned short*)alloc((size_t)NROWS*512*2);
  unsigned short* BrIh0 = (unsigned short*)alloc((size_t)GDIM*512*2);
  unsigned short* Br0   = (unsigned short*)alloc((size_t)GDIM*512*2);
  unsigned short* Br1   = (unsigned short*)alloc((size_t)GDIM*1024*2);
  float* bias0r = (float*)alloc(GDIM*4);
  float* br1    = (float*)alloc(GDIM*4);
  unsigned short* P0 = (unsigned short*)alloc((size_t)NROWS*GDIM*2);
  unsigned short* h0 = (unsigned short*)alloc((size_t)2*NROWS*HDIM*2);
  unsigned short* h1 = (unsigned short*)alloc((size_t)2*NROWS*HDIM*2);
  float* c0 = (float*)alloc((size_t)NROWS*HDIM*4);   // fallback path only
  float* c1 = (float*)alloc((size_t)NROWS*HDIM*4);   // fallback path only
  unsigned* bar = (unsigned*)alloc(8192);            // 64 bands x 128B
  if (off > ws_size) return;  // workspace too small — would need fallback

  (void)hipFuncSetAttribute(reinterpret_cast<const void*>(persist_kernel),
                            hipFuncAttributeMaxDynamicSharedMemorySize, 147456);
  (void)hipFuncSetAttribute(reinterpret_cast<const void*>(step_kernel),
                            hipFuncAttributeMaxDynamicSharedMemorySize, 131072);

  // zero h0,h1,c0,c1,bar (contiguous: 8+8+8+8 MB + 8 KB)
  hipMemsetAsync(h0, 0, (size_t)33562624, stream);

  prep_weights<<<2048, 256, 0, stream>>>(wih0, whh0, bih0, bhh0,
                                         wih1, whh1, bih1, bhh1,
                                         BrIh0, Br0, Br1, bias0r, br1);
  gather_embed<<<4096, 256, 0, stream>>>(enc, tbl, E);
  p0_gemm<<<512, 256, 0, stream>>>(E, BrIh0, bias0r, P0);

  int occ = 0;
  hipError_t oe = hipOccupancyMaxActiveBlocksPerMultiprocessor(
      &occ, reinterpret_cast<const void*>(persist_kernel), 512, 147456);
  bool coop = (oe == hipSuccess && occ >= 1);
  if (coop){
    void* kargs[] = {&h0, &h1, &Br0, &Br1, &P0, &br1, &out, &bar};
    hipError_t le = hipLaunchCooperativeKernel(
        reinterpret_cast<const void*>(persist_kernel),
        dim3(256), dim3(512), kargs, 147456, stream);
    if (le != hipSuccess) coop = false;
  }
  if (!coop){
    for (int tau = 0; tau <= 33; ++tau){
      const int grid = (tau == 0 || tau == 33) ? 128 : 256;
      const int boff = (tau == 33) ? 128 : 0;
      step_kernel<<<grid, 512, 131072, stream>>>(h0, h1, c0, c1, Br0, Br1,
                                                 P0, br1, out, tau, boff);
    }
  }
}

// Round 6
// 1740.565 us; speedup vs baseline: 1.0015x; 1.0015x over previous
//
#include <hip/hip_runtime.h>
#include <stdint.h>

#define NROWS 4096   // S*B
#define HDIM  512
#define GDIM  2048   // 4*H
#define WWIN  32

typedef __attribute__((ext_vector_type(8))) short short8;
typedef __attribute__((ext_vector_type(4))) float f32x4;
typedef __attribute__((ext_vector_type(2))) unsigned long long u64x2;

__device__ __forceinline__ unsigned short f2bf(float x){
  union { float f; unsigned int u; } v; v.f = x;
  unsigned int u = v.u + 0x7fffu + ((v.u >> 16) & 1u);
  return (unsigned short)(u >> 16);
}
__device__ __forceinline__ float bf2f(unsigned short u){
  union { unsigned int u; float f; } v; v.u = ((unsigned int)u) << 16; return v.f;
}

__device__ __forceinline__ void gld16(const void* g, void* l){
  __builtin_amdgcn_global_load_lds(
      (const __attribute__((address_space(1))) unsigned int*)g,
      (__attribute__((address_space(3))) unsigned int*)l, 16, 0, 0);
}

// L1-bypassing, L2-hitting 8B load (sc0): for cross-block h reads within an XCD.
__device__ __forceinline__ unsigned long long ld_sc0_b64(const void* p){
  unsigned long long r;
  asm volatile("global_load_dwordx2 %0, %1, off sc0"
               : "=v"(r) : "v"(p) : "memory");
  return r;
}

__device__ __forceinline__ float sigm(float x){ return 1.f/(1.f + __expf(-x)); }
__device__ __forceinline__ float tanh_f(float x){ return 1.f - 2.f/(1.f + __expf(2.f*x)); }

// ---- fence-free per-XCD sync: 32 blocks of one XCD share a monotonic counter.
// h moves through the XCD's own L2 (plain stores + sc0 loads, same L2);
// __syncthreads drains vmcnt (stores reach L2 = XCD coherence point) before
// arrival. Counter itself uses agent atomics (tiny traffic). No cache fences
// -> L2 (weights/P0/h) never invalidated.
__device__ __forceinline__ void band_sync(unsigned* ctr, unsigned target){
  __syncthreads();
  if (threadIdx.x == 0){
    __hip_atomic_fetch_add(ctr, 1u, __ATOMIC_RELAXED, __HIP_MEMORY_SCOPE_AGENT);
    while (__hip_atomic_load(ctr, __ATOMIC_RELAXED, __HIP_MEMORY_SCOPE_AGENT) < target)
      __builtin_amdgcn_s_sleep(2);
  }
  asm volatile("" ::: "memory");
  __syncthreads();
}

// ------------- double-buffered 128x128 GEMM core (bf16, BT weight layout) -----
// (p0_gemm only)
__device__ __forceinline__ void gemm_tile_db(
    const char* A0, const char* A1, const char* Bsrc,
    int ldbB, int nk, int r0, int c0,
    char* smem, int wr, int wc, int lane, f32x4 acc[4][4])
{
  const int tid = threadIdx.x;
  const int oo0 = tid * 16;
  const int srow = oo0 >> 7;
  const int scb  = oo0 & 127;
  const size_t aOff = (size_t)(r0 + srow) * 1024 + scb;
  const size_t bOff = (size_t)(c0 + srow) * (size_t)ldbB + scb;

  auto STAGE = [&](int kk, int buf){
    const char* Ap = (kk < 8) ? A0 : A1;
    const size_t kbA = (size_t)(kk & 7) * 128;
    const size_t kbB = (size_t)kk * 128;
    char* AsB = smem + buf * 16384;
    char* BsB = smem + 32768 + buf * 16384;
    #pragma unroll
    for (int i = 0; i < 4; ++i){
      const size_t rstep = (size_t)i * 32;
      gld16(Ap   + aOff + rstep * 1024          + kbA, AsB + i*4096 + oo0);
      gld16(Bsrc + bOff + rstep * (size_t)ldbB  + kbB, BsB + i*4096 + oo0);
    }
  };

  STAGE(0, 0);
  __syncthreads();

  const int lr = lane & 15;
  const int lk = (lane >> 4) * 8;

  for (int kk = 0; kk < nk; ++kk){
    const int cur = kk & 1;
    if (kk + 1 < nk) STAGE(kk + 1, cur ^ 1);

    const unsigned short* As = (const unsigned short*)(smem + cur*16384);
    const unsigned short* Bs = (const unsigned short*)(smem + 32768 + cur*16384);
    short8 a[2][4], b[2][4];
    #pragma unroll
    for (int h = 0; h < 2; ++h){
      const int k32 = h * 32;
      #pragma unroll
      for (int m = 0; m < 4; ++m)
        a[h][m] = *(const short8*)(As + (64*wr + 16*m + lr)*64 + k32 + lk);
      #pragma unroll
      for (int n = 0; n < 4; ++n)
        b[h][n] = *(const short8*)(Bs + (64*wc + 16*n + lr)*64 + k32 + lk);
    }
    __builtin_amdgcn_s_setprio(1);
    #pragma unroll
    for (int h = 0; h < 2; ++h)
      #pragma unroll
      for (int m = 0; m < 4; ++m)
        #pragma unroll
        for (int n = 0; n < 4; ++n)
          acc[m][n] = __builtin_amdgcn_mfma_f32_16x16x32_bf16(a[h][m], b[h][n], acc[m][n], 0, 0, 0);
    __builtin_amdgcn_s_setprio(0);

    __syncthreads();
  }
}

// ---------------- prep: reorder weights gate-interleaved, cast bf16 -----------
__global__ void __launch_bounds__(256) prep_weights(
    const float* wih0, const float* whh0, const float* bih0, const float* bhh0,
    const float* wih1, const float* whh1, const float* bih1, const float* bhh1,
    unsigned short* BrIh0, unsigned short* Br0, unsigned short* Br1,
    float* bias0r, float* br1)
{
  const int j = blockIdx.x;
  const int g = j & 3, hd = j >> 2;
  const int r = g*512 + hd;
  for (int k = threadIdx.x; k < 512; k += 256){
    BrIh0[(size_t)j*512 + k]      = f2bf(wih0[(size_t)r*512 + k]);
    Br0  [(size_t)j*512 + k]      = f2bf(whh0[(size_t)r*512 + k]);
    Br1  [(size_t)j*1024 + k]     = f2bf(wih1[(size_t)r*512 + k]);
    Br1  [(size_t)j*1024 + 512+k] = f2bf(whh1[(size_t)r*512 + k]);
  }
  if (threadIdx.x == 0){
    bias0r[j] = bih0[r] + bhh0[r];
    br1[j]    = bih1[r] + bhh1[r];
  }
}

// ---------------- embedding gather (fp32 -> bf16) -----------------------------
__global__ void __launch_bounds__(256) gather_embed(const int* enc, const float* tbl,
                                                    unsigned short* E)
{
  const int n = blockIdx.x;
  const int idx = enc[n];
  const float* src = tbl + (size_t)idx * 512;
  unsigned short* dst = E + (size_t)n * 512;
  for (int e = threadIdx.x; e < 512; e += 256) dst[e] = f2bf(src[e]);
}

// ---------------- P0 = E @ BrIh0^T + bias0r (bf16 out, interleaved cols) ------
__global__ void __launch_bounds__(256) p0_gemm(const unsigned short* E,
                                               const unsigned short* BrIh0,
                                               const float* bias0r,
                                               unsigned short* P0)
{
  __shared__ __align__(16) char smem[65536];
  const int tid  = threadIdx.x;
  const int lane = tid & 63, wid = tid >> 6;
  const int wr = wid >> 1, wc = wid & 1;
  const int bid = blockIdx.x;
  const int r0 = (bid >> 4) * 128, c0 = (bid & 15) * 128;
  f32x4 acc[4][4] = {};
  gemm_tile_db((const char*)E, nullptr, (const char*)BrIh0, 1024, 8,
               r0, c0, smem, wr, wc, lane, acc);
  #pragma unroll
  for (int m = 0; m < 4; ++m){
    const int rowb = r0 + 64*wr + 16*m + ((lane >> 4) << 2);
    #pragma unroll
    for (int n = 0; n < 4; ++n){
      const int colb = c0 + 64*wc + 16*n + (lane & 15);
      const float bs = bias0r[colb];
      #pragma unroll
      for (int r = 0; r < 4; ++r)
        P0[(size_t)(rowb + r)*GDIM + colb] = f2bf(acc[m][n][r] + bs);
    }
  }
}

// ============== persistent fused kernel v4: XCD-local bands ===================
// 256 blocks x 512 thr; 96KB LDS forces 1 block/CU -> exactly 32 blocks/XCD.
// Each block reads its PHYSICAL XCD (s_getreg XCC_ID, m09) and claims a roster
// slot -> role {layer, sub(2x256rows), colg(8x256cols)} assigned WITHIN the
// XCD. XCD x owns rows [x*512, x*512+512): h0/h1 for the band are produced and
// consumed only on this XCD -> h flows through the XCD's own L2 (plain stores
// + sc0 loads). Weights/P0 via normal L2-cached path; fence-free sync keeps L2
// warm across all 33 steps. GEMM: 256x256, 8 waves, BK=32, ring-2; A reg-staged
// (sc0) -> swizzled ds_write_b128; B via gld16. c-state in registers.
__global__ void __launch_bounds__(512, 1) persist_kernel(
    unsigned short* h0, unsigned short* h1,
    const unsigned short* Br0, const unsigned short* Br1,
    const unsigned short* P0, const float* br1, float* out, unsigned* bar)
{
  extern __shared__ __align__(16) char smem[];
  __shared__ int role_s;

  const int tid  = threadIdx.x;
  if (tid == 0){
    unsigned xcc;
    asm volatile("s_getreg_b32 %0, hwreg(HW_REG_XCC_ID)" : "=s"(xcc));
    xcc &= 7u;
    unsigned slot = __hip_atomic_fetch_add(&bar[xcc * 32], 1u, __ATOMIC_RELAXED,
                                           __HIP_MEMORY_SCOPE_AGENT);
    role_s = (int)((xcc << 5) | (slot & 31u));
  }
  __syncthreads();
  const int role = role_s;
  const int xcc = role >> 5, j = role & 31;
  const bool L1 = (j & 1);
  const int sub  = (j >> 1) & 1;
  const int colg = j >> 2;
  const int r0   = xcc * 512 + sub * 256;
  const int c0v  = colg * 256;

  const int lane = tid & 63, wid = tid >> 6;
  const int wm = wid >> 2, wn = wid & 3;          // 2x4 waves over 256x256
  const int lr = lane & 15, sl = lane >> 4;
  const int ph = (sl ^ ((lr >> 1) & 3)) << 4;     // swizzled ds_read slot
  const int laneA = (wm*128 + lr) * 64 + ph;
  const int laneB = (wn*64  + lr) * 64 + ph;

  // A reg-staging: thread covers row ar, logical 16B slots s0, s0+1
  const int ar   = tid >> 1;                      // 0..255
  const int s0   = (tid & 1) * 2;
  const int akey = (ar >> 1) & 3;
  const int off0 = ar*64 + ((s0 ^ akey) << 4);
  const int off1 = ar*64 + (((s0 + 1) ^ akey) << 4);

  // B staging (gld16 linear dest, inverse-swizzled source) — R2-proven
  const int srowB  = tid >> 2;
  const int sbyteB = ((tid & 3) ^ ((tid >> 3) & 3)) << 4;

  const char* Bp  = (const char*)(L1 ? Br1 : Br0);
  const int  ldbB = L1 ? 2048 : 1024;
  const int  nkt  = L1 ? 32 : 16;

  unsigned* ctr = bar + 512 + xcc * 32;   // sync counters after roster region

  float creg[4][8];
  #pragma unroll
  for (int p = 0; p < 4; ++p)
    #pragma unroll
    for (int q = 0; q < 8; ++q) creg[p][q] = 0.f;

  for (int tau = 0; tau <= 33; ++tau){
    const bool active = L1 ? (tau >= 1) : (tau <= 32);
    if (active){
      const int t  = L1 ? (tau - 1) : tau;
      const int pr = (tau + 1) & 1, pw = tau & 1;
      const unsigned short* hA0 = h0 + (size_t)pr * (NROWS*HDIM);
      const unsigned short* hA1 = h1 + (size_t)pr * (NROWS*HDIM);

      unsigned long long A0r, A1r, A2r, A3r;
      auto issueA = [&](int kt2){
        const unsigned short* hs; int kB;
        if (!L1 || kt2 < 16){ hs = hA0; kB = kt2 * 64; }
        else                { hs = hA1; kB = (kt2 - 16) * 64; }
        const char* base = (const char*)hs + (size_t)(r0 + ar) * 1024 + kB + s0*16;
        A0r = ld_sc0_b64(base);
        A1r = ld_sc0_b64(base + 8);
        A2r = ld_sc0_b64(base + 16);
        A3r = ld_sc0_b64(base + 24);
      };
      auto writeA = [&](int kt2){
        char* Ab = smem + (size_t)(kt2 & 1) * 16384;
        u64x2 v0; v0[0] = A0r; v0[1] = A1r;
        u64x2 v1; v1[0] = A2r; v1[1] = A3r;
        *(u64x2*)(Ab + off0) = v0;
        *(u64x2*)(Ab + off1) = v1;
      };
      auto issueB = [&](int kt2){
        char* d = smem + 32768 + (size_t)(kt2 & 1) * 16384 + tid * 16;
        #pragma unroll
        for (int c = 0; c < 2; ++c)
          gld16(Bp + (size_t)(c0v + c*128 + srowB) * (size_t)ldbB + kt2*64 + sbyteB,
                d + c*8192);
      };

      f32x4 acc[8][4] = {};

      // prologue
      issueA(0);
      asm volatile("s_waitcnt vmcnt(0)" ::: "memory");
      __builtin_amdgcn_sched_barrier(0);
      writeA(0);
      issueB(0);
      issueA(1);
      asm volatile("s_waitcnt vmcnt(4)" ::: "memory");   // B(0) landed
      asm volatile("s_waitcnt lgkmcnt(0)" ::: "memory");
      __builtin_amdgcn_s_barrier();

      for (int kt = 0; kt < nkt; ++kt){
        const bool n1 = (kt + 1) < nkt, n2 = (kt + 2) < nkt;
        if (n1) issueB(kt + 1);

        const char* Ab = smem + (size_t)(kt & 1) * 16384;
        const char* Bb = smem + 32768 + (size_t)(kt & 1) * 16384;
        short8 a[8], b[4];
        #pragma unroll
        for (int m = 0; m < 8; ++m)
          a[m] = *(const short8*)(Ab + laneA + m*1024);
        #pragma unroll
        for (int n = 0; n < 4; ++n)
          b[n] = *(const short8*)(Bb + laneB + n*1024);

        __builtin_amdgcn_s_setprio(1);
        #pragma unroll
        for (int m = 0; m < 8; ++m)
          #pragma unroll
          for (int n = 0; n < 4; ++n)
            acc[m][n] = __builtin_amdgcn_mfma_f32_16x16x32_bf16(a[m], b[n], acc[m][n], 0, 0, 0);
        __builtin_amdgcn_s_setprio(0);

        if (n1){
          asm volatile("s_waitcnt vmcnt(2)" ::: "memory");   // A(kt+1) regs done
          __builtin_amdgcn_sched_barrier(0);
          writeA(kt + 1);
          if (n2){
            issueA(kt + 2);
            asm volatile("s_waitcnt vmcnt(4)" ::: "memory"); // B(kt+1) landed
          } else {
            asm volatile("s_waitcnt vmcnt(0)" ::: "memory");
          }
        } else {
          asm volatile("s_waitcnt vmcnt(0)" ::: "memory");
        }
        asm volatile("s_waitcnt lgkmcnt(0)" ::: "memory");
        __builtin_amdgcn_s_barrier();
      }

      // ---- epilogue: LSTM pointwise; c in regs; h via plain stores (L2) ----
      float* GLDS = (float*)smem;
      const int GST = 68;                      // 256 x 68 x 4B = 69.6KB
      unsigned short* hw = (L1 ? h1 : h0) + (size_t)pw * (NROWS*HDIM);
      const bool finalStep = (L1 && t == 32);
      const int cbase = c0v >> 2;

      #pragma unroll
      for (int pass = 0; pass < 4; ++pass){
        __syncthreads();
        if (wn == pass){
          #pragma unroll
          for (int m = 0; m < 8; ++m){
            const int rowb = wm*128 + m*16 + (sl << 2);
            #pragma unroll
            for (int n = 0; n < 4; ++n){
              const int colb = n*16 + lr;
              const f32x4 v = acc[m][n];
              #pragma unroll
              for (int r = 0; r < 4; ++r)
                GLDS[(rowb + r)*GST + colb] = v[r];
            }
          }
        }
        __syncthreads();
        #pragma unroll
        for (int it = 0; it < 8; ++it){
          const int cid = it*512 + tid;        // 4096 cells: 256 rows x 16 hd
          const int row = cid >> 4;
          const int l   = cid & 15;
          const int rowg = r0 + row;
          const int hd   = cbase + pass*16 + l;
          float4 gv = *(const float4*)&GLDS[row*GST + 4*l];
          float gi = gv.x, gf = gv.y, gg = gv.z, go = gv.w;
          const int sI = rowg >> 3;
          const int bb = rowg & 7;
          const int pos = sI - WWIN + t;
          if (!L1){
            const int p0r = (pos < 0 ? 0 : pos)*8 + bb;
            const ushort4 pv = *(const ushort4*)&P0[(size_t)p0r*GDIM + 4*hd];
            gi += bf2f(pv.x); gf += bf2f(pv.y); gg += bf2f(pv.z); go += bf2f(pv.w);
          } else {
            float4 bv = *(const float4*)&br1[4*hd];
            gi += bv.x; gf += bv.y; gg += bv.z; go += bv.w;
          }
          float cp = creg[pass][it];
          float i_ = sigm(gi), f_ = sigm(gf), g_ = tanh_f(gg), o_ = sigm(go);
          float cn = f_*cp + i_*g_;
          float hn = o_*tanh_f(cn);
          if (pos < 0){ cn = 0.f; hn = 0.f; }
          creg[pass][it] = cn;
          const size_t sidx = (size_t)rowg*HDIM + hd;
          if (finalStep) out[sidx] = hn;
          else           hw[sidx]  = f2bf(hn);
        }
      }
    }
    if (tau != 33) band_sync(ctr, 32u * (unsigned)(tau + 1));
  }
}

// ---------------- fallback per-step kernel (non-cooperative path) -------------
__global__ void __launch_bounds__(512, 2) step_kernel(
    unsigned short* h0, unsigned short* h1, float* c0b, float* c1b,
    const unsigned short* Br0, const unsigned short* Br1,
    const unsigned short* P0, const float* br1, float* out, int tau, int bidOff)
{
  extern __shared__ __align__(16) char smem[];

  const int x = blockIdx.x & 7, kq = blockIdx.x >> 3;
  int wk;
  if (gridDim.x == 256) wk = ((kq & 1) << 7) + x * 16 + (kq >> 1);
  else                  wk = x * 16 + kq;
  wk += bidOff;

  const bool L1 = (wk >= 128);
  const int t  = L1 ? (tau - 1) : tau;
  const int pr = (tau + 1) & 1, pw = tau & 1;
  const int lb = L1 ? (wk - 128) : wk;
  const int r0  = (lb >> 3) * 256;
  const int c0v = (lb & 7) * 256;

  const int tid  = threadIdx.x;
  const int lane = tid & 63;
  const int wid  = tid >> 6;
  const int wm = wid >> 2, wn = wid & 3;
  const int lr = lane & 15, sl = lane >> 4;

  const unsigned short* hA0 = h0 + (size_t)pr * (NROWS*HDIM);
  const unsigned short* hA1 = h1 + (size_t)pr * (NROWS*HDIM);
  const char* Bp  = (const char*)(L1 ? Br1 : Br0);
  const int  ldbB = L1 ? 2048 : 1024;
  const int  nkt  = L1 ? 32 : 16;

  const int srow  = tid >> 2;
  const int sbyte = ((tid & 3) ^ ((tid >> 3) & 3)) << 4;
  const int ph    = (sl ^ ((lr >> 1) & 3)) << 4;
  const int laneA = (wm*128 + lr) * 64 + ph;
  const int laneB = (wn*64  + lr) * 64 + ph;

  auto STAGE_A = [&](int kt2, int c){
    const char* Ap; int kB;
    if (!L1 || kt2 < 16){ Ap = (const char*)hA0; kB = kt2 * 64; }
    else                { Ap = (const char*)hA1; kB = (kt2 - 16) * 64; }
    gld16(Ap + (size_t)(r0 + c*128 + srow) * 1024 + kB + sbyte,
          smem + (size_t)(kt2 & 3) * 32768 + c*8192 + tid*16);
  };
  auto STAGE_B = [&](int kt2, int c){
    gld16(Bp + (size_t)(c0v + c*128 + srow) * (size_t)ldbB + kt2*64 + sbyte,
          smem + (size_t)(kt2 & 3) * 32768 + 16384 + c*8192 + tid*16);
  };

  f32x4 acc[8][4] = {};

  STAGE_A(0,0); STAGE_A(0,1); STAGE_B(0,0); STAGE_B(0,1);
  STAGE_A(1,0); STAGE_A(1,1); STAGE_B(1,0); STAGE_B(1,1);
  asm volatile("s_waitcnt vmcnt(4)" ::: "memory");
  __builtin_amdgcn_s_barrier();

  for (int kt = 0; kt < nkt; ++kt){
    const char* bufp = smem + (size_t)(kt & 3) * 32768;
    const bool st = (kt + 2) < nkt;
    short8 a0[4], a1[4], b[4];

    #pragma unroll
    for (int m = 0; m < 4; ++m) a0[m] = *(const short8*)(bufp + laneA + m*1024);
    #pragma unroll
    for (int n = 0; n < 4; ++n) b[n]  = *(const short8*)(bufp + 16384 + laneB + n*1024);
    if (st){ STAGE_A(kt+2, 0); STAGE_A(kt+2, 1); }
    __builtin_amdgcn_s_barrier();
    asm volatile("s_waitcnt lgkmcnt(0)" ::: "memory");
    __builtin_amdgcn_sched_barrier(0);
    __builtin_amdgcn_s_setprio(1);
    #pragma unroll
    for (int m = 0; m < 4; ++m)
      #pragma unroll
      for (int n = 0; n < 4; ++n)
        acc[m][n] = __builtin_amdgcn_mfma_f32_16x16x32_bf16(a0[m], b[n], acc[m][n], 0, 0, 0);
    __builtin_amdgcn_s_setprio(0);
    __builtin_amdgcn_s_barrier();

    #pragma unroll
    for (int m = 0; m < 4; ++m) a1[m] = *(const short8*)(bufp + laneA + (4+m)*1024);
    if (st){
      STAGE_B(kt+2, 0); STAGE_B(kt+2, 1);
      asm volatile("s_waitcnt vmcnt(4)" ::: "memory");
    } else {
      asm volatile("s_waitcnt vmcnt(0)" ::: "memory");
    }
    __builtin_amdgcn_s_barrier();
    asm volatile("s_waitcnt lgkmcnt(0)" ::: "memory");
    __builtin_amdgcn_sched_barrier(0);
    __builtin_amdgcn_s_setprio(1);
    #pragma unroll
    for (int m = 0; m < 4; ++m)
      #pragma unroll
      for (int n = 0; n < 4; ++n)
        acc[4+m][n] = __builtin_amdgcn_mfma_f32_16x16x32_bf16(a1[m], b[n], acc[4+m][n], 0, 0, 0);
    __builtin_amdgcn_s_setprio(0);
    __builtin_amdgcn_s_barrier();
  }

  float* GLDS = (float*)smem;
  const int GST = 68;
  float* cbuf = L1 ? c1b : c0b;
  unsigned short* hw = (L1 ? h1 : h0) + (size_t)pw * (NROWS*HDIM);
  const bool finalStep = (L1 && t == 32);

  for (int pass = 0; pass < 4; ++pass){
    __syncthreads();
    if (wn == pass){
      #pragma unroll
      for (int m = 0; m < 8; ++m){
        const int rowb = wm*128 + m*16 + (sl << 2);
        #pragma unroll
        for (int n = 0; n < 4; ++n){
          const int colb = n*16 + lr;
          const f32x4 v = acc[m][n];
          #pragma unroll
          for (int r = 0; r < 4; ++r)
            GLDS[(rowb + r)*GST + colb] = v[r];
        }
      }
    }
    __syncthreads();
    #pragma unroll
    for (int it = 0; it < 8; ++it){
      const int cid = it*512 + tid;
      const int row = cid >> 4;
      const int l   = cid & 15;
      const int rowg = r0 + row;
      const int hd   = (c0v >> 2) + pass*16 + l;
      float4 gv = *(const float4*)&GLDS[row*GST + 4*l];
      float gi = gv.x, gf = gv.y, gg = gv.z, go = gv.w;
      const int s  = rowg >> 3;
      const int bb = rowg & 7;
      const int pos = s - WWIN + t;
      if (!L1){
        const int p0r = (pos < 0 ? 0 : pos)*8 + bb;
        const ushort4 pv = *(const ushort4*)&P0[(size_t)p0r*GDIM + 4*hd];
        gi += bf2f(pv.x); gf += bf2f(pv.y); gg += bf2f(pv.z); go += bf2f(pv.w);
      } else {
        float4 bv = *(const float4*)&br1[4*hd];
        gi += bv.x; gf += bv.y; gg += bv.z; go += bv.w;
      }
      const size_t sidx = (size_t)rowg*HDIM + hd;
      float cp = cbuf[sidx];
      float i_ = sigm(gi), f_ = sigm(gf), g_ = tanh_f(gg), o_ = sigm(go);
      float cn = f_*cp + i_*g_;
      float hn = o_*tanh_f(cn);
      if (pos < 0){ cn = 0.f; hn = 0.f; }
      cbuf[sidx] = cn;
      if (finalStep) out[sidx] = hn;
      else           hw[sidx]  = f2bf(hn);
    }
  }
}

extern "C" void kernel_launch(void* const* d_in, const int* in_sizes, int n_in,
                              void* d_out, int out_size, void* d_ws, size_t ws_size,
                              hipStream_t stream)
{
  const int*   enc  = (const int*)d_in[0];
  const float* tbl  = (const float*)d_in[1];
  const float* wih0 = (const float*)d_in[2];
  const float* whh0 = (const float*)d_in[3];
  const float* bih0 = (const float*)d_in[4];
  const float* bhh0 = (const float*)d_in[5];
  const float* wih1 = (const float*)d_in[6];
  const float* whh1 = (const float*)d_in[7];
  const float* bih1 = (const float*)d_in[8];
  const float* bhh1 = (const float*)d_in[9];
  float* out = (float*)d_out;

  char* ws = (char*)d_ws;
  size_t off = 0;
  auto alloc = [&](size_t bytes){
    char* p = ws + off; off += (bytes + 255) & ~(size_t)255; return p;
  };
  unsigned short* E     = (unsigned short*)alloc((size_t)NROWS*512*2);
  unsigned short* BrIh0 = (unsigned short*)alloc((size_t)GDIM*512*2);
  unsigned short* Br0   = (unsigned short*)alloc((size_t)GDIM*512*2);
  unsigned short* Br1   = (unsigned short*)alloc((size_t)GDIM*1024*2);
  float* bias0r = (float*)alloc(GDIM*4);
  float* br1    = (float*)alloc(GDIM*4);
  unsigned short* P0 = (unsigned short*)alloc((size_t)NROWS*GDIM*2);
  unsigned short* h0 = (unsigned short*)alloc((size_t)2*NROWS*HDIM*2);
  unsigned short* h1 = (unsigned short*)alloc((size_t)2*NROWS*HDIM*2);
  float* c0 = (float*)alloc((size_t)NROWS*HDIM*4);   // fallback path only
  float* c1 = (float*)alloc((size_t)NROWS*HDIM*4);   // fallback path only
  unsigned* bar = (unsigned*)alloc(8192);            // roster + sync counters
  if (off > ws_size) return;  // workspace too small — would need fallback

  (void)hipFuncSetAttribute(reinterpret_cast<const void*>(persist_kernel),
                            hipFuncAttributeMaxDynamicSharedMemorySize, 98304);
  (void)hipFuncSetAttribute(reinterpret_cast<const void*>(step_kernel),
                            hipFuncAttributeMaxDynamicSharedMemorySize, 131072);

  // zero h0,h1,c0,c1,bar (contiguous: 8+8+8+8 MB + 8 KB)
  hipMemsetAsync(h0, 0, (size_t)33562624, stream);

  prep_weights<<<2048, 256, 0, stream>>>(wih0, whh0, bih0, bhh0,
                                         wih1, whh1, bih1, bhh1,
                                         BrIh0, Br0, Br1, bias0r, br1);
  gather_embed<<<4096, 256, 0, stream>>>(enc, tbl, E);
  p0_gemm<<<512, 256, 0, stream>>>(E, BrIh0, bias0r, P0);

  int occ = 0;
  hipError_t oe = hipOccupancyMaxActiveBlocksPerMultiprocessor(
      &occ, reinterpret_cast<const void*>(persist_kernel), 512, 98304);
  bool coop = (oe == hipSuccess && occ >= 1);
  if (coop){
    void* kargs[] = {&h0, &h1, &Br0, &Br1, &P0, &br1, &out, &bar};
    hipError_t le = hipLaunchCooperativeKernel(
        reinterpret_cast<const void*>(persist_kernel),
        dim3(256), dim3(512), kargs, 98304, stream);
    if (le != hipSuccess) coop = false;
  }
  if (!coop){
    for (int tau = 0; tau <= 33; ++tau){
      const int grid = (tau == 0 || tau == 33) ? 128 : 256;
      const int boff = (tau == 33) ? 128 : 0;
      step_kernel<<<grid, 512, 131072, stream>>>(h0, h1, c0, c1, Br0, Br1,
                                                 P0, br1, out, tau, boff);
    }
  }
}

// Round 7
// 1739.834 us; speedup vs baseline: 1.0019x; 1.0004x over previous
//
#include <hip/hip_runtime.h>
#include <stdint.h>

#define NROWS 4096   // S*B
#define HDIM  512
#define GDIM  2048   // 4*H
#define WWIN  32

typedef __attribute__((ext_vector_type(8))) short short8;
typedef __attribute__((ext_vector_type(4))) float f32x4;

__device__ __forceinline__ unsigned short f2bf(float x){
  union { float f; unsigned int u; } v; v.f = x;
  unsigned int u = v.u + 0x7fffu + ((v.u >> 16) & 1u);
  return (unsigned short)(u >> 16);
}
__device__ __forceinline__ float bf2f(unsigned short u){
  union { unsigned int u; float f; } v; v.u = ((unsigned int)u) << 16; return v.f;
}

__device__ __forceinline__ void gld16(const void* g, void* l){
  __builtin_amdgcn_global_load_lds(
      (const __attribute__((address_space(1))) unsigned int*)g,
      (__attribute__((address_space(3))) unsigned int*)l, 16, 0, 0);
}

__device__ __forceinline__ float sigm(float x){ return 1.f/(1.f + __expf(-x)); }
__device__ __forceinline__ float tanh_f(float x){ return 1.f - 2.f/(1.f + __expf(2.f*x)); }

// ---- fence-free per-XCD sync (64 blocks/XCD share one monotonic counter) ----
// h is produced and consumed on the same XCD (roster) -> flows through that
// XCD's L2; __syncthreads drains vmcnt (stores at L2 = XCD coherence point)
// before arrival. No cache fences -> L2 (weights/P0/h) never invalidated.
__device__ __forceinline__ void band_sync(unsigned* ctr, unsigned target){
  __syncthreads();
  if (threadIdx.x == 0){
    __hip_atomic_fetch_add(ctr, 1u, __ATOMIC_RELAXED, __HIP_MEMORY_SCOPE_AGENT);
    while (__hip_atomic_load(ctr, __ATOMIC_RELAXED, __HIP_MEMORY_SCOPE_AGENT) < target)
      __builtin_amdgcn_s_sleep(2);
  }
  asm volatile("" ::: "memory");
  __syncthreads();
}

// ------------- double-buffered 128x128 GEMM core (bf16, BT weight layout) -----
// (p0_gemm only)
__device__ __forceinline__ void gemm_tile_db(
    const char* A0, const char* A1, const char* Bsrc,
    int ldbB, int nk, int r0, int c0,
    char* smem, int wr, int wc, int lane, f32x4 acc[4][4])
{
  const int tid = threadIdx.x;
  const int oo0 = tid * 16;
  const int srow = oo0 >> 7;
  const int scb  = oo0 & 127;
  const size_t aOff = (size_t)(r0 + srow) * 1024 + scb;
  const size_t bOff = (size_t)(c0 + srow) * (size_t)ldbB + scb;

  auto STAGE = [&](int kk, int buf){
    const char* Ap = (kk < 8) ? A0 : A1;
    const size_t kbA = (size_t)(kk & 7) * 128;
    const size_t kbB = (size_t)kk * 128;
    char* AsB = smem + buf * 16384;
    char* BsB = smem + 32768 + buf * 16384;
    #pragma unroll
    for (int i = 0; i < 4; ++i){
      const size_t rstep = (size_t)i * 32;
      gld16(Ap   + aOff + rstep * 1024          + kbA, AsB + i*4096 + oo0);
      gld16(Bsrc + bOff + rstep * (size_t)ldbB  + kbB, BsB + i*4096 + oo0);
    }
  };

  STAGE(0, 0);
  __syncthreads();

  const int lr = lane & 15;
  const int lk = (lane >> 4) * 8;

  for (int kk = 0; kk < nk; ++kk){
    const int cur = kk & 1;
    if (kk + 1 < nk) STAGE(kk + 1, cur ^ 1);

    const unsigned short* As = (const unsigned short*)(smem + cur*16384);
    const unsigned short* Bs = (const unsigned short*)(smem + 32768 + cur*16384);
    short8 a[2][4], b[2][4];
    #pragma unroll
    for (int h = 0; h < 2; ++h){
      const int k32 = h * 32;
      #pragma unroll
      for (int m = 0; m < 4; ++m)
        a[h][m] = *(const short8*)(As + (64*wr + 16*m + lr)*64 + k32 + lk);
      #pragma unroll
      for (int n = 0; n < 4; ++n)
        b[h][n] = *(const short8*)(Bs + (64*wc + 16*n + lr)*64 + k32 + lk);
    }
    __builtin_amdgcn_s_setprio(1);
    #pragma unroll
    for (int h = 0; h < 2; ++h)
      #pragma unroll
      for (int m = 0; m < 4; ++m)
        #pragma unroll
        for (int n = 0; n < 4; ++n)
          acc[m][n] = __builtin_amdgcn_mfma_f32_16x16x32_bf16(a[h][m], b[h][n], acc[m][n], 0, 0, 0);
    __builtin_amdgcn_s_setprio(0);

    __syncthreads();
  }
}

// ---------------- prep: reorder weights gate-interleaved, cast bf16 -----------
__global__ void __launch_bounds__(256) prep_weights(
    const float* wih0, const float* whh0, const float* bih0, const float* bhh0,
    const float* wih1, const float* whh1, const float* bih1, const float* bhh1,
    unsigned short* BrIh0, unsigned short* Br0, unsigned short* Br1,
    float* bias0r, float* br1)
{
  const int j = blockIdx.x;
  const int g = j & 3, hd = j >> 2;
  const int r = g*512 + hd;
  for (int k = threadIdx.x; k < 512; k += 256){
    BrIh0[(size_t)j*512 + k]      = f2bf(wih0[(size_t)r*512 + k]);
    Br0  [(size_t)j*512 + k]      = f2bf(whh0[(size_t)r*512 + k]);
    Br1  [(size_t)j*1024 + k]     = f2bf(wih1[(size_t)r*512 + k]);
    Br1  [(size_t)j*1024 + 512+k] = f2bf(whh1[(size_t)r*512 + k]);
  }
  if (threadIdx.x == 0){
    bias0r[j] = bih0[r] + bhh0[r];
    br1[j]    = bih1[r] + bhh1[r];
  }
}

// ---------------- embedding gather (fp32 -> bf16) -----------------------------
__global__ void __launch_bounds__(256) gather_embed(const int* enc, const float* tbl,
                                                    unsigned short* E)
{
  const int n = blockIdx.x;
  const int idx = enc[n];
  const float* src = tbl + (size_t)idx * 512;
  unsigned short* dst = E + (size_t)n * 512;
  for (int e = threadIdx.x; e < 512; e += 256) dst[e] = f2bf(src[e]);
}

// ---------------- P0 = E @ BrIh0^T + bias0r (bf16 out, interleaved cols) ------
__global__ void __launch_bounds__(256) p0_gemm(const unsigned short* E,
                                               const unsigned short* BrIh0,
                                               const float* bias0r,
                                               unsigned short* P0)
{
  __shared__ __align__(16) char smem[65536];
  const int tid  = threadIdx.x;
  const int lane = tid & 63, wid = tid >> 6;
  const int wr = wid >> 1, wc = wid & 1;
  const int bid = blockIdx.x;
  const int r0 = (bid >> 4) * 128, c0 = (bid & 15) * 128;
  f32x4 acc[4][4] = {};
  gemm_tile_db((const char*)E, nullptr, (const char*)BrIh0, 1024, 8,
               r0, c0, smem, wr, wc, lane, acc);
  #pragma unroll
  for (int m = 0; m < 4; ++m){
    const int rowb = r0 + 64*wr + 16*m + ((lane >> 4) << 2);
    #pragma unroll
    for (int n = 0; n < 4; ++n){
      const int colb = c0 + 64*wc + 16*n + (lane & 15);
      const float bs = bias0r[colb];
      #pragma unroll
      for (int r = 0; r < 4; ++r)
        P0[(size_t)(rowb + r)*GDIM + colb] = f2bf(acc[m][n][r] + bs);
    }
  }
}

// ============ persistent fused kernel v5: 2 blocks/CU, fine-phase =============
// 512 blocks x 256 thr (4 waves), 72KB LDS -> 2 blocks/CU: one block's
// prologue/epilogue/sync/L3-stream stalls are covered by its CU-mate's GEMM.
// Roster: 64 slots/XCD = {layer} x {4 row-subs of 128} x {8 colgs of 256} ->
// h XCD-local (L2), one L0 + one L1 block per CU (balanced). Tile 128x256,
// per-wave 128x64 (acc[8][4]). kt loop (BK=32): 2 phases x 16 MFMA, ring-3 A
// (8KB) + ring-3 B (16KB) staged 2 kt ahead, vmcnt(6) counted (never 0
// mid-loop), lgkmcnt(0)+sched_barrier before MFMA, setprio, 2 barriers/phase.
__global__ void __launch_bounds__(256, 2) persist_kernel(
    unsigned short* h0, unsigned short* h1,
    const unsigned short* Br0, const unsigned short* Br1,
    const unsigned short* P0, const float* br1, float* out, unsigned* bar)
{
  extern __shared__ __align__(16) char smem[];
  __shared__ int role_s;

  const int tid = threadIdx.x;
  if (tid == 0){
    unsigned xcc;
    asm volatile("s_getreg_b32 %0, hwreg(HW_REG_XCC_ID)" : "=s"(xcc));
    xcc &= 7u;
    unsigned slot = __hip_atomic_fetch_add(&bar[xcc * 32], 1u, __ATOMIC_RELAXED,
                                           __HIP_MEMORY_SCOPE_AGENT);
    role_s = (int)((xcc << 6) | (slot & 63u));
  }
  __syncthreads();
  const int role = role_s;
  const int xcc = role >> 6, j = role & 63;
  const bool L1 = (j & 1);
  const int sub  = (j >> 1) & 3;                 // 4 row-subs of 128
  const int colg = j >> 3;                       // 8 col-groups of 256
  const int r0   = xcc * 512 + sub * 128;
  const int c0v  = colg * 256;

  const int lane = tid & 63, wn = tid >> 6;      // 4 waves, 1x4 over cols
  const int lr = lane & 15, sl = lane >> 4;
  const int ph = (sl ^ ((lr >> 1) & 3)) << 4;    // swizzled ds_read slot
  const int laneA = lr * 64 + ph;                // A shared by all waves
  const int laneB = (wn*64 + lr) * 64 + ph;

  // staging thread map (256 thr, 4KB chunks): row = tid>>2 (+64/chunk),
  // phys slot16 = tid&3, logical = phys ^ key(row) -> pre-swizzled source.
  const int srowS = tid >> 2;
  const int ls16  = ((tid & 3) ^ ((tid >> 3) & 3)) << 4;

  const char* Bp  = (const char*)(L1 ? Br1 : Br0);
  const int  ldbB = L1 ? 2048 : 1024;
  const int  nkt  = L1 ? 32 : 16;

  unsigned* ctr = bar + 512 + xcc * 32;

  float creg[4][8];
  #pragma unroll
  for (int p = 0; p < 4; ++p)
    #pragma unroll
    for (int q = 0; q < 8; ++q) creg[p][q] = 0.f;

  for (int tau = 0; tau <= 33; ++tau){
    const bool active = L1 ? (tau >= 1) : (tau <= 32);
    if (active){
      const int t  = L1 ? (tau - 1) : tau;
      const int pr = (tau + 1) & 1, pw = tau & 1;
      const unsigned short* hA0 = h0 + (size_t)pr * (NROWS*HDIM);
      const unsigned short* hA1 = h1 + (size_t)pr * (NROWS*HDIM);

      auto STAGE_A = [&](int kt2){
        char* d = smem + (size_t)(kt2 % 3) * 8192 + tid * 16;
        const unsigned short* hs; int kB;
        if (!L1 || kt2 < 16){ hs = hA0; kB = kt2 * 64; }
        else                { hs = hA1; kB = (kt2 - 16) * 64; }
        const char* s = (const char*)hs + (size_t)(r0 + srowS) * 1024 + kB + ls16;
        gld16(s, d);
        gld16(s + (size_t)64 * 1024, d + 4096);
      };
      auto STAGE_Bu = [&](int kt2, int u){
        char* d = smem + 24576 + (size_t)(kt2 % 3) * 16384 + u * 8192 + tid * 16;
        const char* s = Bp + (size_t)(c0v + u*128 + srowS) * (size_t)ldbB
                           + kt2 * 64 + ls16;
        gld16(s, d);
        gld16(s + (size_t)64 * (size_t)ldbB, d + 4096);
      };

      f32x4 acc[8][4] = {};

      // prologue: stage kt0, kt1 fully (12 loads); wait kt0 (6 newest = kt1)
      STAGE_A(0); STAGE_Bu(0,0); STAGE_Bu(0,1);
      STAGE_A(1); STAGE_Bu(1,0); STAGE_Bu(1,1);
      asm volatile("s_waitcnt vmcnt(6)" ::: "memory");
      __builtin_amdgcn_s_barrier();

      for (int kt = 0; kt < nkt; ++kt){
        const char* Ab = smem + (size_t)(kt % 3) * 8192;
        const char* Bb = smem + 24576 + (size_t)(kt % 3) * 16384;
        const bool st = (kt + 2) < nkt;
        short8 b[4], a0[4], a1[4];

        // ---- phase 0: rows 0-63 ----
        #pragma unroll
        for (int n = 0; n < 4; ++n) b[n]  = *(const short8*)(Bb + laneB + n*1024);
        #pragma unroll
        for (int m = 0; m < 4; ++m) a0[m] = *(const short8*)(Ab + laneA + m*1024);
        if (st) STAGE_Bu(kt + 2, 0);
        __builtin_amdgcn_s_barrier();
        asm volatile("s_waitcnt lgkmcnt(0)" ::: "memory");
        __builtin_amdgcn_sched_barrier(0);
        __builtin_amdgcn_s_setprio(1);
        #pragma unroll
        for (int m = 0; m < 4; ++m)
          #pragma unroll
          for (int n = 0; n < 4; ++n)
            acc[m][n] = __builtin_amdgcn_mfma_f32_16x16x32_bf16(a0[m], b[n], acc[m][n], 0, 0, 0);
        __builtin_amdgcn_s_setprio(0);
        __builtin_amdgcn_s_barrier();

        // ---- phase 1: rows 64-127 ----
        #pragma unroll
        for (int m = 0; m < 4; ++m) a1[m] = *(const short8*)(Ab + laneA + 4096 + m*1024);
        if (st){ STAGE_Bu(kt + 2, 1); STAGE_A(kt + 2); }
        __builtin_amdgcn_s_barrier();
        asm volatile("s_waitcnt lgkmcnt(0)" ::: "memory");
        __builtin_amdgcn_sched_barrier(0);
        __builtin_amdgcn_s_setprio(1);
        #pragma unroll
        for (int m = 0; m < 4; ++m)
          #pragma unroll
          for (int n = 0; n < 4; ++n)
            acc[4+m][n] = __builtin_amdgcn_mfma_f32_16x16x32_bf16(a1[m], b[n], acc[4+m][n], 0, 0, 0);
        __builtin_amdgcn_s_setprio(0);
        if (st) asm volatile("s_waitcnt vmcnt(6)" ::: "memory");  // kt+1 landed
        else    asm volatile("s_waitcnt vmcnt(0)" ::: "memory");
        __builtin_amdgcn_s_barrier();
      }

      // ---- epilogue: LSTM pointwise; c in regs; h via plain stores (L2) ----
      float* GLDS = (float*)smem;
      const int GST = 68;                        // 128 x 68 x 4B = 34.8KB
      unsigned short* hw = (L1 ? h1 : h0) + (size_t)pw * (NROWS*HDIM);
      const bool finalStep = (L1 && t == 32);
      const int cbase = c0v >> 2;                // colg*64

      #pragma unroll
      for (int pass = 0; pass < 4; ++pass){
        __syncthreads();
        if (wn == pass){
          #pragma unroll
          for (int m = 0; m < 8; ++m){
            const int rowb = m*16 + (sl << 2);
            #pragma unroll
            for (int n = 0; n < 4; ++n){
              const int colb = n*16 + lr;
              const f32x4 v = acc[m][n];
              #pragma unroll
              for (int r = 0; r < 4; ++r)
                GLDS[(rowb + r)*GST + colb] = v[r];
            }
          }
        }
        __syncthreads();
        #pragma unroll
        for (int it = 0; it < 8; ++it){
          const int cid = it*256 + tid;          // 2048 cells: 128 rows x 16 hd
          const int row = cid >> 4;
          const int l   = cid & 15;
          const int rowg = r0 + row;
          const int hd   = cbase + pass*16 + l;
          float4 gv = *(const float4*)&GLDS[row*GST + 4*l];
          float gi = gv.x, gf = gv.y, gg = gv.z, go = gv.w;
          const int sI = rowg >> 3;
          const int bb = rowg & 7;
          const int pos = sI - WWIN + t;
          if (!L1){
            const int p0r = (pos < 0 ? 0 : pos)*8 + bb;
            const ushort4 pv = *(const ushort4*)&P0[(size_t)p0r*GDIM + 4*hd];
            gi += bf2f(pv.x); gf += bf2f(pv.y); gg += bf2f(pv.z); go += bf2f(pv.w);
          } else {
            float4 bv = *(const float4*)&br1[4*hd];
            gi += bv.x; gf += bv.y; gg += bv.z; go += bv.w;
          }
          float cp = creg[pass][it];
          float i_ = sigm(gi), f_ = sigm(gf), g_ = tanh_f(gg), o_ = sigm(go);
          float cn = f_*cp + i_*g_;
          float hn = o_*tanh_f(cn);
          if (pos < 0){ cn = 0.f; hn = 0.f; }
          creg[pass][it] = cn;
          const size_t sidx = (size_t)rowg*HDIM + hd;
          if (finalStep) out[sidx] = hn;
          else           hw[sidx]  = f2bf(hn);
        }
      }
    }
    if (tau != 33) band_sync(ctr, 64u * (unsigned)(tau + 1));
  }
}

// ---------------- fallback per-step kernel (non-cooperative path) -------------
__global__ void __launch_bounds__(512, 2) step_kernel(
    unsigned short* h0, unsigned short* h1, float* c0b, float* c1b,
    const unsigned short* Br0, const unsigned short* Br1,
    const unsigned short* P0, const float* br1, float* out, int tau, int bidOff)
{
  extern __shared__ __align__(16) char smem[];

  const int x = blockIdx.x & 7, kq = blockIdx.x >> 3;
  int wk;
  if (gridDim.x == 256) wk = ((kq & 1) << 7) + x * 16 + (kq >> 1);
  else                  wk = x * 16 + kq;
  wk += bidOff;

  const bool L1 = (wk >= 128);
  const int t  = L1 ? (tau - 1) : tau;
  const int pr = (tau + 1) & 1, pw = tau & 1;
  const int lb = L1 ? (wk - 128) : wk;
  const int r0  = (lb >> 3) * 256;
  const int c0v = (lb & 7) * 256;

  const int tid  = threadIdx.x;
  const int lane = tid & 63;
  const int wid  = tid >> 6;
  const int wm = wid >> 2, wn = wid & 3;
  const int lr = lane & 15, sl = lane >> 4;

  const unsigned short* hA0 = h0 + (size_t)pr * (NROWS*HDIM);
  const unsigned short* hA1 = h1 + (size_t)pr * (NROWS*HDIM);
  const char* Bp  = (const char*)(L1 ? Br1 : Br0);
  const int  ldbB = L1 ? 2048 : 1024;
  const int  nkt  = L1 ? 32 : 16;

  const int srow  = tid >> 2;
  const int sbyte = ((tid & 3) ^ ((tid >> 3) & 3)) << 4;
  const int ph    = (sl ^ ((lr >> 1) & 3)) << 4;
  const int laneA = (wm*128 + lr) * 64 + ph;
  const int laneB = (wn*64  + lr) * 64 + ph;

  auto STAGE_A = [&](int kt2, int c){
    const char* Ap; int kB;
    if (!L1 || kt2 < 16){ Ap = (const char*)hA0; kB = kt2 * 64; }
    else                { Ap = (const char*)hA1; kB = (kt2 - 16) * 64; }
    gld16(Ap + (size_t)(r0 + c*128 + srow) * 1024 + kB + sbyte,
          smem + (size_t)(kt2 & 3) * 32768 + c*8192 + tid*16);
  };
  auto STAGE_B = [&](int kt2, int c){
    gld16(Bp + (size_t)(c0v + c*128 + srow) * (size_t)ldbB + kt2*64 + sbyte,
          smem + (size_t)(kt2 & 3) * 32768 + 16384 + c*8192 + tid*16);
  };

  f32x4 acc[8][4] = {};

  STAGE_A(0,0); STAGE_A(0,1); STAGE_B(0,0); STAGE_B(0,1);
  STAGE_A(1,0); STAGE_A(1,1); STAGE_B(1,0); STAGE_B(1,1);
  asm volatile("s_waitcnt vmcnt(4)" ::: "memory");
  __builtin_amdgcn_s_barrier();

  for (int kt = 0; kt < nkt; ++kt){
    const char* bufp = smem + (size_t)(kt & 3) * 32768;
    const bool st = (kt + 2) < nkt;
    short8 a0[4], a1[4], b[4];

    #pragma unroll
    for (int m = 0; m < 4; ++m) a0[m] = *(const short8*)(bufp + laneA + m*1024);
    #pragma unroll
    for (int n = 0; n < 4; ++n) b[n]  = *(const short8*)(bufp + 16384 + laneB + n*1024);
    if (st){ STAGE_A(kt+2, 0); STAGE_A(kt+2, 1); }
    __builtin_amdgcn_s_barrier();
    asm volatile("s_waitcnt lgkmcnt(0)" ::: "memory");
    __builtin_amdgcn_sched_barrier(0);
    __builtin_amdgcn_s_setprio(1);
    #pragma unroll
    for (int m = 0; m < 4; ++m)
      #pragma unroll
      for (int n = 0; n < 4; ++n)
        acc[m][n] = __builtin_amdgcn_mfma_f32_16x16x32_bf16(a0[m], b[n], acc[m][n], 0, 0, 0);
    __builtin_amdgcn_s_setprio(0);
    __builtin_amdgcn_s_barrier();

    #pragma unroll
    for (int m = 0; m < 4; ++m) a1[m] = *(const short8*)(bufp + laneA + (4+m)*1024);
    if (st){
      STAGE_B(kt+2, 0); STAGE_B(kt+2, 1);
      asm volatile("s_waitcnt vmcnt(4)" ::: "memory");
    } else {
      asm volatile("s_waitcnt vmcnt(0)" ::: "memory");
    }
    __builtin_amdgcn_s_barrier();
    asm volatile("s_waitcnt lgkmcnt(0)" ::: "memory");
    __builtin_amdgcn_sched_barrier(0);
    __builtin_amdgcn_s_setprio(1);
    #pragma unroll
    for (int m = 0; m < 4; ++m)
      #pragma unroll
      for (int n = 0; n < 4; ++n)
        acc[4+m][n] = __builtin_amdgcn_mfma_f32_16x16x32_bf16(a1[m], b[n], acc[4+m][n], 0, 0, 0);
    __builtin_amdgcn_s_setprio(0);
    __builtin_amdgcn_s_barrier();
  }

  float* GLDS = (float*)smem;
  const int GST = 68;
  float* cbuf = L1 ? c1b : c0b;
  unsigned short* hw = (L1 ? h1 : h0) + (size_t)pw * (NROWS*HDIM);
  const bool finalStep = (L1 && t == 32);

  for (int pass = 0; pass < 4; ++pass){
    __syncthreads();
    if (wn == pass){
      #pragma unroll
      for (int m = 0; m < 8; ++m){
        const int rowb = wm*128 + m*16 + (sl << 2);
        #pragma unroll
        for (int n = 0; n < 4; ++n){
          const int colb = n*16 + lr;
          const f32x4 v = acc[m][n];
          #pragma unroll
          for (int r = 0; r < 4; ++r)
            GLDS[(rowb + r)*GST + colb] = v[r];
        }
      }
    }
    __syncthreads();
    #pragma unroll
    for (int it = 0; it < 8; ++it){
      const int cid = it*512 + tid;
      const int row = cid >> 4;
      const int l   = cid & 15;
      const int rowg = r0 + row;
      const int hd   = (c0v >> 2) + pass*16 + l;
      float4 gv = *(const float4*)&GLDS[row*GST + 4*l];
      float gi = gv.x, gf = gv.y, gg = gv.z, go = gv.w;
      const int s  = rowg >> 3;
      const int bb = rowg & 7;
      const int pos = s - WWIN + t;
      if (!L1){
        const int p0r = (pos < 0 ? 0 : pos)*8 + bb;
        const ushort4 pv = *(const ushort4*)&P0[(size_t)p0r*GDIM + 4*hd];
        gi += bf2f(pv.x); gf += bf2f(pv.y); gg += bf2f(pv.z); go += bf2f(pv.w);
      } else {
        float4 bv = *(const float4*)&br1[4*hd];
        gi += bv.x; gf += bv.y; gg += bv.z; go += bv.w;
      }
      const size_t sidx = (size_t)rowg*HDIM + hd;
      float cp = cbuf[sidx];
      float i_ = sigm(gi), f_ = sigm(gf), g_ = tanh_f(gg), o_ = sigm(go);
      float cn = f_*cp + i_*g_;
      float hn = o_*tanh_f(cn);
      if (pos < 0){ cn = 0.f; hn = 0.f; }
      cbuf[sidx] = cn;
      if (finalStep) out[sidx] = hn;
      else           hw[sidx]  = f2bf(hn);
    }
  }
}

extern "C" void kernel_launch(void* const* d_in, const int* in_sizes, int n_in,
                              void* d_out, int out_size, void* d_ws, size_t ws_size,
                              hipStream_t stream)
{
  const int*   enc  = (const int*)d_in[0];
  const float* tbl  = (const float*)d_in[1];
  const float* wih0 = (const float*)d_in[2];
  const float* whh0 = (const float*)d_in[3];
  const float* bih0 = (const float*)d_in[4];
  const float* bhh0 = (const float*)d_in[5];
  const float* wih1 = (const float*)d_in[6];
  const float* whh1 = (const float*)d_in[7];
  const float* bih1 = (const float*)d_in[8];
  const float* bhh1 = (const float*)d_in[9];
  float* out = (float*)d_out;

  char* ws = (char*)d_ws;
  size_t off = 0;
  auto alloc = [&](size_t bytes){
    char* p = ws + off; off += (bytes + 255) & ~(size_t)255; return p;
  };
  unsigned short* E     = (unsigned short*)alloc((size_t)NROWS*512*2);
  unsigned short* BrIh0 = (unsigned short*)alloc((size_t)GDIM*512*2);
  unsigned short* Br0   = (unsigned short*)alloc((size_t)GDIM*512*2);
  unsigned short* Br1   = (unsigned short*)alloc((size_t)GDIM*1024*2);
  float* bias0r = (float*)alloc(GDIM*4);
  float* br1    = (float*)alloc(GDIM*4);
  unsigned short* P0 = (unsigned short*)alloc((size_t)NROWS*GDIM*2);
  unsigned short* h0 = (unsigned short*)alloc((size_t)2*NROWS*HDIM*2);
  unsigned short* h1 = (unsigned short*)alloc((size_t)2*NROWS*HDIM*2);
  float* c0 = (float*)alloc((size_t)NROWS*HDIM*4);   // fallback path only
  float* c1 = (float*)alloc((size_t)NROWS*HDIM*4);   // fallback path only
  unsigned* bar = (unsigned*)alloc(8192);            // roster + sync counters
  if (off > ws_size) return;  // workspace too small — would need fallback

  (void)hipFuncSetAttribute(reinterpret_cast<const void*>(persist_kernel),
                            hipFuncAttributeMaxDynamicSharedMemorySize, 73728);
  (void)hipFuncSetAttribute(reinterpret_cast<const void*>(step_kernel),
                            hipFuncAttributeMaxDynamicSharedMemorySize, 131072);

  // zero h0,h1,c0,c1,bar (contiguous: 8+8+8+8 MB + 8 KB)
  hipMemsetAsync(h0, 0, (size_t)33562624, stream);

  prep_weights<<<2048, 256, 0, stream>>>(wih0, whh0, bih0, bhh0,
                                         wih1, whh1, bih1, bhh1,
                                         BrIh0, Br0, Br1, bias0r, br1);
  gather_embed<<<4096, 256, 0, stream>>>(enc, tbl, E);
  p0_gemm<<<512, 256, 0, stream>>>(E, BrIh0, bias0r, P0);

  int occ = 0;
  hipError_t oe = hipOccupancyMaxActiveBlocksPerMultiprocessor(
      &occ, reinterpret_cast<const void*>(persist_kernel), 256, 73728);
  bool coop = (oe == hipSuccess && occ >= 2);
  if (coop){
    void* kargs[] = {&h0, &h1, &Br0, &Br1, &P0, &br1, &out, &bar};
    hipError_t le = hipLaunchCooperativeKernel(
        reinterpret_cast<const void*>(persist_kernel),
        dim3(512), dim3(256), kargs, 73728, stream);
    if (le != hipSuccess) coop = false;
  }
  if (!coop){
    for (int tau = 0; tau <= 33; ++tau){
      const int grid = (tau == 0 || tau == 33) ? 128 : 256;
      const int boff = (tau == 33) ? 128 : 0;
      step_kernel<<<grid, 512, 131072, stream>>>(h0, h1, c0, c1, Br0, Br1,
                                                 P0, br1, out, tau, boff);
    }
  }
}